// Round 6
// baseline (49.716 us; speedup 1.0000x reference)
//
#include <hip/hip_runtime.h>
#include <hip/hip_bf16.h>

// Geometry: B=8, S=256, T=64, H=128. Only einsum channel 0 survives -> 4-tap
// pool with W[0],W[6],W[12],W[18]; per-position min/max normalize over t=64;
// bilinear align_corners upsample 128->256.
//
// Fused: one block per (b, 32x32 output tile). Stage 1 computes the 18x18
// pooled positions the tile needs into LDS (bf16, 41.5 KB). Stage 2 blends
// from LDS and writes float4 stores.
//
// Round-5 confirmed baseline 48.9 us (FETCH~82MB WRITE~134MB, 0 bank
// conflicts). This round: stage-1 position loop is a compile-time 6-iter
// predicated unroll (was runtime trip count -> rolled -> load-latency
// serialized), and __launch_bounds__(1024, 8) pins VGPR <= 64 so the extra
// in-flight loads can't drop occupancy below 2 blocks/CU (32 waves).
//
// NOTE: plain stores, NOT __builtin_nontemporal_store (replay-flake caution).

typedef float f32x4 __attribute__((ext_vector_type(4)));
typedef unsigned short u16x4 __attribute__((ext_vector_type(4)));

#define BB 8
#define SS 256
#define TT 64
#define HH 128
#define TILE 32
#define PL 18   // worst-case pooled span for 32 output rows (floor-diff 16 + i1 + slack)

static __device__ __forceinline__ unsigned short f2bf(float f) {
    unsigned int u = __float_as_uint(f);
    u += 0x7FFFu + ((u >> 16) & 1u);   // RNE
    return (unsigned short)(u >> 16);
}
static __device__ __forceinline__ float bf2f(unsigned short h) {
    return __uint_as_float(((unsigned int)h) << 16);
}

__global__ __launch_bounds__(1024, 8) void fused_pool_up_kernel(
    const float* __restrict__ in, const float* __restrict__ W,
    float* __restrict__ out)
{
    __shared__ unsigned short plds[PL * PL * TT];   // bf16 pooled tile, 41.5 KB

    const int tile_j = blockIdx.x;
    const int tile_i = blockIdx.y;
    const int b      = blockIdx.z;
    const int tid    = threadIdx.x;

    const float scale = 127.0f / 255.0f;
    const int i_base = tile_i * TILE;
    const int j_base = tile_j * TILE;
    // same f32 expression as the per-pixel floor -> consistent, monotone
    const int p_i_lo = (int)((float)i_base * scale);
    const int p_j_lo = (int)((float)j_base * scale);

    const float w0 = W[0];    // p=0 -> (2h  , 2w  )
    const float w1 = W[6];    // p=1 -> (2h  , 2w+1)
    const float w2 = W[12];   // p=2 -> (2h+1, 2w  )
    const float w3 = W[18];   // p=3 -> (2h+1, 2w+1)

    // ---------- stage 1: pooled 18x18 -> LDS (bf16) ----------
    // 16 threads per pooled position (4 t-values each, float4 loads);
    // min/max over t = 4-step shfl_xor within the 16-lane group.
    // Compile-time unroll: 324 positions / 64 groups -> 6 predicated iters.
    const int grp = tid >> 4;          // position-group id (0..63)
    const int t4  = (tid & 15) * 4;    // t offset

    #pragma unroll
    for (int it = 0; it < 6; ++it) {
        const int pp = grp + it * 64;
        if (pp < PL * PL) {            // uniform within each 16-lane group
            const int pr  = pp / PL;
            const int pc  = pp - pr * PL;
            const int gpr = min(p_i_lo + pr, HH - 1);
            const int gpc = min(p_j_lo + pc, HH - 1);

            const size_t base = (((size_t)b * SS + 2 * gpr) * SS + 2 * gpc) * TT + t4;
            const f32x4 va = *(const f32x4*)(in + base);
            const f32x4 vb = *(const f32x4*)(in + base + TT);
            const f32x4 vc = *(const f32x4*)(in + base + (size_t)SS * TT);
            const f32x4 vd = *(const f32x4*)(in + base + (size_t)SS * TT + TT);

            const f32x4 v = w0 * va + w1 * vb + w2 * vc + w3 * vd;

            float mn = fminf(fminf(v.x, v.y), fminf(v.z, v.w));
            #pragma unroll
            for (int off = 1; off < 16; off <<= 1)
                mn = fminf(mn, __shfl_xor(mn, off));

            const f32x4 s = v - mn;

            float mx = fmaxf(fmaxf(s.x, s.y), fmaxf(s.z, s.w));
            #pragma unroll
            for (int off = 1; off < 16; off <<= 1)
                mx = fmaxf(mx, __shfl_xor(mx, off));

            const float inv = 1.0f / mx;
            u16x4 h;
            h.x = f2bf(s.x * inv);
            h.y = f2bf(s.y * inv);
            h.z = f2bf(s.z * inv);
            h.w = f2bf(s.w * inv);
            *(u16x4*)(plds + (pr * PL + pc) * TT + t4) = h;
        }
    }

    __syncthreads();

    // ---------- stage 2: bilinear blend -> out ----------
    const int t4i = tid & 15;          // float4 index along t
    const int jl  = (tid >> 4) & 31;   // local output col
    const int ih  = tid >> 9;          // 0/1, interleaved local rows

    const int   j   = j_base + jl;
    const float pjf = (float)j * scale;
    const int   j0  = (int)pjf;
    const float wj  = pjf - (float)j0;
    const int   j1  = min(j0 + 1, HH - 1);
    const int   j0l = j0 - p_j_lo;
    const int   j1l = j1 - p_j_lo;

    const u16x4* lds4 = (const u16x4*)plds;  // pooled position stride = 16 u16x4

    #pragma unroll
    for (int k = 0; k < 16; ++k) {
        const int   il  = 2 * k + ih;
        const int   i   = i_base + il;
        const float pif = (float)i * scale;
        const int   i0  = (int)pif;
        const float wi  = pif - (float)i0;
        const int   i1  = min(i0 + 1, HH - 1);
        const int   i0l = i0 - p_i_lo;
        const int   i1l = i1 - p_i_lo;

        const u16x4 h00 = lds4[(i0l * PL + j0l) * 16 + t4i];
        const u16x4 h01 = lds4[(i0l * PL + j1l) * 16 + t4i];
        const u16x4 h10 = lds4[(i1l * PL + j0l) * 16 + t4i];
        const u16x4 h11 = lds4[(i1l * PL + j1l) * 16 + t4i];

        f32x4 v00 = { bf2f(h00.x), bf2f(h00.y), bf2f(h00.z), bf2f(h00.w) };
        f32x4 v01 = { bf2f(h01.x), bf2f(h01.y), bf2f(h01.z), bf2f(h01.w) };
        f32x4 v10 = { bf2f(h10.x), bf2f(h10.y), bf2f(h10.z), bf2f(h10.w) };
        f32x4 v11 = { bf2f(h11.x), bf2f(h11.y), bf2f(h11.z), bf2f(h11.w) };

        // interpolate along H first, then W (reference order)
        const f32x4 a2 = v00 * (1.0f - wi) + v10 * wi;
        const f32x4 c2 = v01 * (1.0f - wi) + v11 * wi;
        const f32x4 r2 = a2 * (1.0f - wj) + c2 * wj;

        const size_t oidx = (((size_t)b * SS + i) * SS + j) * TT + 4 * t4i;
        *(f32x4*)(out + oidx) = r2;   // plain store (see NOTE above)
    }
}

extern "C" void kernel_launch(void* const* d_in, const int* in_sizes, int n_in,
                              void* d_out, int out_size, void* d_ws, size_t ws_size,
                              hipStream_t stream)
{
    const float* in = (const float*)d_in[0];   // [B,S,S,T] f32
    const float* W  = (const float*)d_in[1];   // [4,6] f32
    float* out      = (float*)d_out;           // [B*S*S, T] f32

    dim3 grid(SS / TILE, SS / TILE, BB);       // 8 x 8 x 8 = 512 blocks
    fused_pool_up_kernel<<<grid, 1024, 0, stream>>>(in, W, out);
}

// Round 7
// 48.209 us; speedup vs baseline: 1.0313x; 1.0313x over previous
//
#include <hip/hip_runtime.h>
#include <hip/hip_bf16.h>

// Geometry: B=8, S=256, T=64, H=128. Only einsum channel 0 survives -> 4-tap
// pool with W[0],W[6],W[12],W[18]; per-position min/max normalize over t=64;
// bilinear align_corners upsample 128->256.
//
// Fused: one block per (b, 32x32 output tile), 18x18 pooled positions in LDS
// (bf16, 41.5 KB). NEW this round: 3-phase pipeline to mix HBM reads and
// writes on the bus (the grid is exactly one residency round, so without
// this ALL blocks do the read-only stage then ALL do the write-only stage):
//   S1a (pooled rows 0..9) -> bar -> { S1b (rows 10..17) + S2a (out rows
//   0..15, needs pooled rows <=9) } -> bar -> S2b (out rows 16..31).
//
// NOTE: plain stores, NOT __builtin_nontemporal_store (replay-flake caution).

typedef float f32x4 __attribute__((ext_vector_type(4)));
typedef unsigned short u16x4 __attribute__((ext_vector_type(4)));

#define BB 8
#define SS 256
#define TT 64
#define HH 128
#define TILE 32
#define PL 18   // pooled span for 32 output rows (16 + i1 + slack)

static __device__ __forceinline__ unsigned short f2bf(float f) {
    unsigned int u = __float_as_uint(f);
    u += 0x7FFFu + ((u >> 16) & 1u);   // RNE
    return (unsigned short)(u >> 16);
}
static __device__ __forceinline__ float bf2f(unsigned short h) {
    return __uint_as_float(((unsigned int)h) << 16);
}

__global__ __launch_bounds__(1024, 8) void fused_pool_up_kernel(
    const float* __restrict__ in, const float* __restrict__ W,
    float* __restrict__ out)
{
    __shared__ unsigned short plds[PL * PL * TT];   // bf16 pooled tile, 41.5 KB

    const int tile_j = blockIdx.x;
    const int tile_i = blockIdx.y;
    const int b      = blockIdx.z;
    const int tid    = threadIdx.x;

    const float scale = 127.0f / 255.0f;
    const int i_base = tile_i * TILE;
    const int j_base = tile_j * TILE;
    const int p_i_lo = (int)((float)i_base * scale);
    const int p_j_lo = (int)((float)j_base * scale);

    const float w0 = W[0];    // p=0 -> (2h  , 2w  )
    const float w1 = W[6];    // p=1 -> (2h  , 2w+1)
    const float w2 = W[12];   // p=2 -> (2h+1, 2w  )
    const float w3 = W[18];   // p=3 -> (2h+1, 2w+1)

    const int grp = tid >> 4;          // position-group id (0..63)
    const int t4  = (tid & 15) * 4;    // t offset

    // ---- stage-1 worker: compute pooled position pp -> LDS (bf16) ----
    auto do_pos = [&](int pp) {
        const int pr  = pp / PL;
        const int pc  = pp - pr * PL;
        const int gpr = min(p_i_lo + pr, HH - 1);
        const int gpc = min(p_j_lo + pc, HH - 1);

        const size_t base = (((size_t)b * SS + 2 * gpr) * SS + 2 * gpc) * TT + t4;
        const f32x4 va = *(const f32x4*)(in + base);
        const f32x4 vb = *(const f32x4*)(in + base + TT);
        const f32x4 vc = *(const f32x4*)(in + base + (size_t)SS * TT);
        const f32x4 vd = *(const f32x4*)(in + base + (size_t)SS * TT + TT);

        const f32x4 v = w0 * va + w1 * vb + w2 * vc + w3 * vd;

        float mn = fminf(fminf(v.x, v.y), fminf(v.z, v.w));
        #pragma unroll
        for (int off = 1; off < 16; off <<= 1)
            mn = fminf(mn, __shfl_xor(mn, off));

        const f32x4 s = v - mn;

        float mx = fmaxf(fmaxf(s.x, s.y), fmaxf(s.z, s.w));
        #pragma unroll
        for (int off = 1; off < 16; off <<= 1)
            mx = fmaxf(mx, __shfl_xor(mx, off));

        const float inv = 1.0f / mx;
        u16x4 h;
        h.x = f2bf(s.x * inv);
        h.y = f2bf(s.y * inv);
        h.z = f2bf(s.z * inv);
        h.w = f2bf(s.w * inv);
        *(u16x4*)(plds + (pr * PL + pc) * TT + t4) = h;
    };

    // ---- stage-2 worker: one output row il (local), all 32 cols ----
    const int t4i = tid & 15;          // float4 index along t
    const int jl  = (tid >> 4) & 31;   // local output col
    const int ih  = tid >> 9;          // 0/1, interleaved local rows

    const int   j   = j_base + jl;
    const float pjf = (float)j * scale;
    const int   j0  = (int)pjf;
    const float wj  = pjf - (float)j0;
    const int   j1  = min(j0 + 1, HH - 1);
    const int   j0l = j0 - p_j_lo;
    const int   j1l = j1 - p_j_lo;

    const u16x4* lds4 = (const u16x4*)plds;  // pooled position stride = 16 u16x4

    auto do_row = [&](int il) {
        const int   i   = i_base + il;
        const float pif = (float)i * scale;
        const int   i0  = (int)pif;
        const float wi  = pif - (float)i0;
        const int   i1  = min(i0 + 1, HH - 1);
        const int   i0l = i0 - p_i_lo;
        const int   i1l = i1 - p_i_lo;

        const u16x4 h00 = lds4[(i0l * PL + j0l) * 16 + t4i];
        const u16x4 h01 = lds4[(i0l * PL + j1l) * 16 + t4i];
        const u16x4 h10 = lds4[(i1l * PL + j0l) * 16 + t4i];
        const u16x4 h11 = lds4[(i1l * PL + j1l) * 16 + t4i];

        f32x4 v00 = { bf2f(h00.x), bf2f(h00.y), bf2f(h00.z), bf2f(h00.w) };
        f32x4 v01 = { bf2f(h01.x), bf2f(h01.y), bf2f(h01.z), bf2f(h01.w) };
        f32x4 v10 = { bf2f(h10.x), bf2f(h10.y), bf2f(h10.z), bf2f(h10.w) };
        f32x4 v11 = { bf2f(h11.x), bf2f(h11.y), bf2f(h11.z), bf2f(h11.w) };

        const f32x4 a2 = v00 * (1.0f - wi) + v10 * wi;
        const f32x4 c2 = v01 * (1.0f - wi) + v11 * wi;
        const f32x4 r2 = a2 * (1.0f - wj) + c2 * wj;

        const size_t oidx = (((size_t)b * SS + i) * SS + j) * TT + 4 * t4i;
        *(f32x4*)(out + oidx) = r2;   // plain store
    };

    // ---------- phase 1: S1a — pooled rows 0..9 (positions 0..179) ----------
    #pragma unroll
    for (int it = 0; it < 3; ++it) {
        const int pp = grp + it * 64;
        if (pp < 180) do_pos(pp);      // uniform within each 16-lane group
    }

    __syncthreads();

    // ---------- phase 2: S1b (rows 10..17) + S2a (out rows 0..15) ----------
    // S1b writes LDS rows 10..17; S2a reads rows <=9 — disjoint, no sync
    // needed between them. Reads (S1b) and writes (S2a) mix on the HBM bus.
    #pragma unroll
    for (int it = 0; it < 3; ++it) {
        const int pp = 180 + grp + it * 64;
        if (pp < PL * PL) do_pos(pp);
    }

    #pragma unroll
    for (int k = 0; k < 8; ++k)
        do_row(2 * k + ih);            // output rows 0..15

    __syncthreads();

    // ---------- phase 3: S2b — output rows 16..31 ----------
    #pragma unroll
    for (int k = 0; k < 8; ++k)
        do_row(16 + 2 * k + ih);
}

extern "C" void kernel_launch(void* const* d_in, const int* in_sizes, int n_in,
                              void* d_out, int out_size, void* d_ws, size_t ws_size,
                              hipStream_t stream)
{
    const float* in = (const float*)d_in[0];   // [B,S,S,T] f32
    const float* W  = (const float*)d_in[1];   // [4,6] f32
    float* out      = (float*)d_out;           // [B*S*S, T] f32

    dim3 grid(SS / TILE, SS / TILE, BB);       // 8 x 8 x 8 = 512 blocks
    fused_pool_up_kernel<<<grid, 1024, 0, stream>>>(in, W, out);
}